// Round 6
// baseline (3635.142 us; speedup 1.0000x reference)
//
#include <hip/hip_runtime.h>
#include <hip/hip_fp16.h>

#define DEVINL __device__ __forceinline__

constexpr int B = 256, S = 512;
constexpr int H0 = 64, H1 = 128, H2 = 256;

typedef _Float16 f16x8 __attribute__((ext_vector_type(8)));
typedef float f32x4 __attribute__((ext_vector_type(4)));
typedef _Float16 h2v __attribute__((ext_vector_type(2)));

DEVINL float fexp2(float x) { return __builtin_amdgcn_exp2f(x); }
DEVINL float frcp(float x) { return __builtin_amdgcn_rcpf(x); }
DEVINL float fsig(float x) { return frcp(1.f + fexp2(-1.44269504088896f * x)); }
DEVINL float ftanh_(float x) { return 1.f - 2.f * frcp(1.f + fexp2(2.88539008177793f * x)); }
DEVINL h2v as_h2(unsigned u) { union { unsigned u; h2v h; } x; x.u = u; return x.h; }
DEVINL float fdot2(unsigned a, unsigned b, float c) {
  return __builtin_amdgcn_fdot2(as_h2(a), as_h2(b), c, false);
}
union FU { uint4 u; f16x8 h; };
DEVINL f16x8 as_f16x8(uint4 u) { FU x; x.u = u; return x.h; }

// Agent-scope (mall-coherent) 8-byte atomic load/store. One aligned dwordx2
// transaction cannot tear, so {seq(hi32) | payload(lo32)} travel together and
// the consumer validates seq in-band (R4-proven flagless protocol).
DEVINL unsigned long long agldull(unsigned long long* p) {
  return __hip_atomic_load(p, __ATOMIC_RELAXED, __HIP_MEMORY_SCOPE_AGENT);
}
DEVINL void agstull(unsigned long long* p, unsigned long long v) {
  __hip_atomic_store(p, v, __ATOMIC_RELAXED, __HIP_MEMORY_SCOPE_AGENT);
}

// Row permutation: r' = mt*16 + quad*4 + reg  ->  channel = r'>>2, gate = r'&3.
// orig torch row = gate*Hch + channel. One lane of the C-frag then holds one
// channel's (i,f,g,o) quad (C: col=lane&15, row=(lane>>4)*4+reg).

// Pack W (fp32 [4*Hch][Kdim], torch gate rows) into fp16 A-frag order:
// wp[(mt*KT+kt)*64+lane] = 8 halves of W'[mt*16+(lane&15)][kt*32+(lane>>4)*8+j]
__global__ __launch_bounds__(256) void pack_frag(const float* __restrict__ w,
    uint4* __restrict__ wp, int Hch, int Kdim, int MT, int KT) {
  int o = blockIdx.x * 256 + threadIdx.x;
  if (o >= MT * KT * 64) return;
  int lane = o & 63, fk = o >> 6;
  int kt = fk % KT, mt = fk / KT;
  int rp = mt * 16 + (lane & 15);
  int orig = (rp & 3) * Hch + (rp >> 2);
  int k0 = kt * 32 + (lane >> 4) * 8;
  unsigned r[4];
#pragma unroll
  for (int p = 0; p < 4; ++p) {
    unsigned lo = __half_as_ushort(__float2half_rn(w[(size_t)orig * Kdim + k0 + 2 * p]));
    unsigned hi = __half_as_ushort(__float2half_rn(w[(size_t)orig * Kdim + k0 + 2 * p + 1]));
    r[p] = lo | (hi << 16);
  }
  uint4 v; v.x = r[0]; v.y = r[1]; v.z = r[2]; v.w = r[3];
  wp[o] = v;
}

__global__ __launch_bounds__(256) void pack_bias(const float* __restrict__ bih,
    const float* __restrict__ bhh, float* __restrict__ bs, int Hch) {
  int rp = blockIdx.x * 256 + threadIdx.x;
  if (rp >= 4 * Hch) return;
  int orig = (rp & 3) * Hch + (rp >> 2);
  bs[rp] = bih[orig] + bhh[orig];
}

__global__ void pack_wl(const float* __restrict__ wl, unsigned* __restrict__ wlp, int n) {
  int i = threadIdx.x;
  if (i < n) {
    unsigned lo = __half_as_ushort(__float2half_rn(wl[2 * i]));
    unsigned hi = __half_as_ushort(__float2half_rn(wl[2 * i + 1]));
    wlp[i] = lo | (hi << 16);
  }
}

__global__ __launch_bounds__(256) void f2h(const float* __restrict__ x,
                                           __half* __restrict__ y, int n8) {
  int i = blockIdx.x * 256 + threadIdx.x;
  if (i >= n8) return;
  float4 a = *(const float4*)(x + i * 8);
  float4 b = *(const float4*)(x + i * 8 + 4);
  __half h[8];
  h[0] = __float2half_rn(a.x); h[1] = __float2half_rn(a.y);
  h[2] = __float2half_rn(a.z); h[3] = __float2half_rn(a.w);
  h[4] = __float2half_rn(b.x); h[5] = __float2half_rn(b.y);
  h[6] = __float2half_rn(b.z); h[7] = __float2half_rn(b.w);
  *(uint4*)(y + i * 8) = *(const uint4*)h;
}

// One layer-stage: embedded input GEMM (own m-tiles, whole chunk -> preT) then
// the weight-stationary recurrent scan. hb (LOCAL channel half only) is
// double-buffered -> ONE barrier per step for both SPLIT modes.
// SPLIT=2 (layer 2): k-split aligned with m-split (K_half = C_half). Each WG
// computes cross partials W[C_peer, K_own]*h_own from LOCAL data, exports them
// (seq-tagged 8B atomics, fire-and-forget), computes own partials + preT,
// imports peer partials (speculative issue right after export; validate after
// own MFMAs), adds, gates. FULL h NEVER crosses WGs. Final out = per-half dot
// partial + 16-scalar tagged exchange (half1 -> half0), one step of slack.
template <int H, int SPLIT, bool FINAL, int KTI>
DEVINL void scan_body(
    int bx, const __half* x, const uint4* wpI, const float* bs,
    const uint4* wp, f32x4* preT, __half* xout, float* out,
    const unsigned* wlp, const float* blp,
    float* sth, float* stc, unsigned long long* xh,
    int Sc, int t0, int first) {
  constexpr int MT = H / 4;           // total m-tiles
  constexpr int MTO = MT / SPLIT;     // owned m-tiles
  constexpr int MTW = MTO / 8;        // per wave
  constexpr int KT = H / 32;          // total k-tiles
  constexpr int KTH = KT / SPLIT;     // owned k-tiles
  constexpr int HLOC = H / SPLIT;     // local channels held in hb
  constexpr int HP = HLOC + 8;
  constexpr int XSLOT = MTW * 4 * 512;  // ull per (par,bt,half) partial slot

  __shared__ __half hb[2][16 * HP];
  __shared__ unsigned wls[FINAL ? (HLOC / 2) : 1];

  const int tid = threadIdx.x, w = tid >> 6, lane = tid & 63;
  const int n16 = lane & 15, quad = lane >> 4;
  int bt, half;
  if constexpr (SPLIT == 2) { bt = bx & 15; half = bx >> 4; }
  else { bt = bx; half = 0; }
  const int b0 = bt * 16;
  const int mbase = half * MTO;
  unsigned long long* dxh = xh + (size_t)2 * 16 * 2 * XSLOT;  // dot slots

  // ---- embedded input GEMM: preT for own m-tiles, all Sc timesteps ----
  {
    constexpr int KI = KTI * 32;
    uint4 wih[MTW][KTI];
#pragma unroll
    for (int im = 0; im < MTW; ++im)
#pragma unroll
      for (int kt = 0; kt < KTI; ++kt)
        wih[im][kt] = wpI[((size_t)(mbase + w * MTW + im) * KTI + kt) * 64 + lane];
    f32x4 bini[MTW];
#pragma unroll
    for (int im = 0; im < MTW; ++im)
      bini[im] = *(const f32x4*)(bs + (mbase + w * MTW + im) * 16 + quad * 4);
    uint4 bfr[KTI];
    {
      const __half* xr = x + ((size_t)(b0 + n16) * S + t0) * KI + quad * 8;
#pragma unroll
      for (int kt = 0; kt < KTI; ++kt) bfr[kt] = *(const uint4*)(xr + kt * 32);
    }
    for (int t = 0; t < Sc; ++t) {
      uint4 cur[KTI];
#pragma unroll
      for (int kt = 0; kt < KTI; ++kt) cur[kt] = bfr[kt];
      if (t + 1 < Sc) {
        const __half* xr = x + ((size_t)(b0 + n16) * S + t0 + t + 1) * KI + quad * 8;
#pragma unroll
        for (int kt = 0; kt < KTI; ++kt) bfr[kt] = *(const uint4*)(xr + kt * 32);
      }
      f32x4 ac[MTW];
#pragma unroll
      for (int im = 0; im < MTW; ++im) ac[im] = bini[im];
#pragma unroll
      for (int kt = 0; kt < KTI; ++kt)
#pragma unroll
        for (int im = 0; im < MTW; ++im)
          ac[im] = __builtin_amdgcn_mfma_f32_16x16x32_f16(as_f16x8(wih[im][kt]),
                                                          as_f16x8(cur[kt]), ac[im], 0, 0, 0);
#pragma unroll
      for (int im = 0; im < MTW; ++im)
        preT[((size_t)(bt * Sc + t) * MT + mbase + w * MTW + im) * 64 + lane] = ac[im];
    }
  }
  asm volatile("s_waitcnt vmcnt(0)" ::: "memory");  // preT at L2 before re-read

  // ---- scan phase ----
  // own rows x own k; (SPLIT=2) cross rows (peer channels) x own k
  uint4 aregO[MTW][KTH];
#pragma unroll
  for (int im = 0; im < MTW; ++im)
#pragma unroll
    for (int kt = 0; kt < KTH; ++kt)
      aregO[im][kt] =
          wp[((size_t)(mbase + w * MTW + im) * KT + half * KTH + kt) * 64 + lane];
  uint4 aregC[SPLIT == 2 ? MTW : 1][SPLIT == 2 ? KTH : 1];
  if constexpr (SPLIT == 2) {
#pragma unroll
    for (int im = 0; im < MTW; ++im)
#pragma unroll
      for (int kt = 0; kt < KTH; ++kt)
        aregC[im][kt] =
            wp[((size_t)((1 - half) * MTO + w * MTW + im) * KT + half * KTH + kt) * 64 + lane];
  }

  if constexpr (FINAL)
    for (int i = tid; i < HLOC / 2; i += 512) wls[i] = wlp[half * (HLOC / 2) + i];

  float cst[MTW];
#pragma unroll
  for (int im = 0; im < MTW; ++im) {
    int ch = (mbase + w * MTW + im) * 4 + quad;
    cst[im] = first ? 0.f : stc[(size_t)(b0 + n16) * H + ch];
  }
  for (int i = tid; i < 16 * HLOC; i += 512) {
    int n = i / HLOC, chl = i % HLOC;
    hb[0][n * HP + chl] =
        first ? __float2half_rn(0.f)
              : __float2half_rn(sth[(size_t)(b0 + n) * H + half * HLOC + chl]);
  }
  __syncthreads();

  const float bl0 = FINAL ? blp[0] : 0.f;

  f32x4 nxt[MTW];
#pragma unroll
  for (int im = 0; im < MTW; ++im)
    nxt[im] = preT[((size_t)(bt * Sc) * MT + mbase + w * MTW + im) * 64 + lane];

  for (int tl = 0; tl < Sc; ++tl) {
    __half* rb = hb[tl & 1];        // own half of h(tl-1)
    __half* wb = hb[(tl + 1) & 1];  // receives own half of h(tl)
    const int hid = t0 + tl;
    const unsigned seq = (unsigned)(hid + 1);
    f32x4 acc[MTW];
#pragma unroll
    for (int im = 0; im < MTW; ++im) acc[im] = nxt[im];
    if (tl + 1 < Sc) {
#pragma unroll
      for (int im = 0; im < MTW; ++im)
        nxt[im] = preT[((size_t)(bt * Sc + tl + 1) * MT + mbase + w * MTW + im) * 64 + lane];
    }

    unsigned long long v[SPLIT == 2 ? MTW : 1][SPLIT == 2 ? 4 : 1];
    unsigned long long* src = nullptr;
    float sOwn = 0.f;
    unsigned long long vdot = 0ull;

    if constexpr (SPLIT == 2) {
      // cross partials from LOCAL h_own(tl-1); export immediately.
      f32x4 accc[MTW];
#pragma unroll
      for (int im = 0; im < MTW; ++im) accc[im] = f32x4{0.f, 0.f, 0.f, 0.f};
#pragma unroll
      for (int kt = 0; kt < KTH; ++kt) {
        f16x8 bf = as_f16x8(*(const uint4*)(rb + n16 * HP + kt * 32 + quad * 8));
#pragma unroll
        for (int im = 0; im < MTW; ++im)
          accc[im] = __builtin_amdgcn_mfma_f32_16x16x32_f16(as_f16x8(aregC[im][kt]), bf,
                                                            accc[im], 0, 0, 0);
      }
      unsigned long long* dst =
          xh + (((size_t)(hid & 1) * 16 + bt) * 2 + half) * XSLOT;
#pragma unroll
      for (int im = 0; im < MTW; ++im)
#pragma unroll
        for (int g = 0; g < 4; ++g)
          agstull(dst + (im * 4 + g) * 512 + w * 64 + lane,
                  ((unsigned long long)seq << 32) |
                      (unsigned long long)__float_as_uint(accc[im][g]));
      // speculative import of peer partials (validated after own MFMAs)
      src = xh + (((size_t)(hid & 1) * 16 + bt) * 2 + (1 - half)) * XSLOT;
#pragma unroll
      for (int im = 0; im < MTW; ++im)
#pragma unroll
        for (int g = 0; g < 4; ++g)
          v[im][g] = agldull(src + (im * 4 + g) * 512 + w * 64 + lane);

      // FINAL dot, part 1: own-half partial of out(tl-1); half1 exports.
      if constexpr (FINAL) {
        if (tl > 0 && w == 0) {
          const int b = lane >> 2, q = lane & 3;
          const unsigned* hrow = (const unsigned*)(rb + b * HP);
          float s = 0.f;
#pragma unroll
          for (int p = 0; p < 16; ++p) s = fdot2(hrow[q * 16 + p], wls[q * 16 + p], s);
          s += __shfl_xor(s, 1); s += __shfl_xor(s, 2);
          sOwn = s;
          unsigned long long* dbase = dxh + ((size_t)((hid - 1) & 1) * 16 + bt) * 16;
          if (half == 1) {
            if (q == 0)
              agstull(dbase + b, ((unsigned long long)(unsigned)hid << 32) |
                                     (unsigned long long)__float_as_uint(s));
          } else {
            if (q == 0) vdot = agldull(dbase + b);
          }
        }
      }
    }

    // own-row MFMAs (k = own half; SPLIT=1 covers everything)
#pragma unroll
    for (int kt = 0; kt < KTH; ++kt) {
      f16x8 bf = as_f16x8(*(const uint4*)(rb + n16 * HP + kt * 32 + quad * 8));
#pragma unroll
      for (int im = 0; im < MTW; ++im)
        acc[im] = __builtin_amdgcn_mfma_f32_16x16x32_f16(as_f16x8(aregO[im][kt]), bf,
                                                         acc[im], 0, 0, 0);
    }

    if constexpr (SPLIT == 2) {
      // validate peer partials, retry on miss, then add.
      for (;;) {
        bool ok = true;
#pragma unroll
        for (int im = 0; im < MTW; ++im)
#pragma unroll
          for (int g = 0; g < 4; ++g) ok &= ((unsigned)(v[im][g] >> 32) == seq);
        if (__all(ok)) break;
        __builtin_amdgcn_s_sleep(1);
#pragma unroll
        for (int im = 0; im < MTW; ++im)
#pragma unroll
          for (int g = 0; g < 4; ++g)
            v[im][g] = agldull(src + (im * 4 + g) * 512 + w * 64 + lane);
      }
#pragma unroll
      for (int im = 0; im < MTW; ++im)
#pragma unroll
        for (int g = 0; g < 4; ++g)
          acc[im][g] += __uint_as_float((unsigned)v[im][g]);
    } else {
      if (tl > 0) {  // SPLIT=1 activation emit (hb holds full h(tl-1))
        if (tid < 16 * (H / 8)) {
          int n = tid / (H / 8), kq = tid % (H / 8);
          uint4 vv = *(const uint4*)(rb + n * HP + kq * 8);
          *(uint4*)(xout + ((size_t)(b0 + n) * S + t0 + tl - 1) * H + kq * 8) = vv;
        }
      }
    }

    // gates (lane holds one channel's i,f,g,o per m-tile)
    __half hh[MTW];
#pragma unroll
    for (int im = 0; im < MTW; ++im) {
      float gi = fsig(acc[im][0]);
      float gf = fsig(acc[im][1]);
      float gg = ftanh_(acc[im][2]);
      float go = fsig(acc[im][3]);
      float cn = gf * cst[im] + gi * gg;
      cst[im] = cn;
      hh[im] = __float2half_rn(go * ftanh_(cn));
    }
#pragma unroll
    for (int im = 0; im < MTW; ++im)
      wb[n16 * HP + (w * MTW + im) * 4 + quad] = hh[im];

    if constexpr (SPLIT == 2 && FINAL) {
      // FINAL dot, part 2: half0 validates peer partial, emits out(tl-1).
      if (tl > 0 && w == 0 && half == 0) {
        const int b = lane >> 2, q = lane & 3;
        unsigned long long* dbase = dxh + ((size_t)((hid - 1) & 1) * 16 + bt) * 16;
        for (;;) {
          bool ok = (q != 0) || ((unsigned)(vdot >> 32) == (unsigned)hid);
          if (__all(ok)) break;
          __builtin_amdgcn_s_sleep(1);
          if (q == 0) vdot = agldull(dbase + b);
        }
        if (q == 0)
          out[(size_t)(b0 + b) * S + (hid - 1)] =
              ftanh_(sOwn + __uint_as_float((unsigned)vdot) + bl0);
      }
    }

    __syncthreads();  // single barrier: wb complete, rb reads done
  }

  __half* fb = hb[Sc & 1];  // own half of h(Sc-1)

  // tail emission
  if constexpr (SPLIT == 2) {
    if constexpr (FINAL) {
      const int tlast = t0 + Sc - 1;
      if (w == 0) {
        const int b = lane >> 2, q = lane & 3;
        const unsigned* hrow = (const unsigned*)(fb + b * HP);
        float s = 0.f;
#pragma unroll
        for (int p = 0; p < 16; ++p) s = fdot2(hrow[q * 16 + p], wls[q * 16 + p], s);
        s += __shfl_xor(s, 1); s += __shfl_xor(s, 2);
        unsigned long long* dbase = dxh + ((size_t)(tlast & 1) * 16 + bt) * 16;
        if (half == 1) {
          if (q == 0)
            agstull(dbase + b, ((unsigned long long)(unsigned)(tlast + 1) << 32) |
                                   (unsigned long long)__float_as_uint(s));
        } else {
          unsigned long long vd = 0ull;
          if (q == 0) vd = agldull(dbase + b);
          for (;;) {
            bool ok = (q != 0) || ((unsigned)(vd >> 32) == (unsigned)(tlast + 1));
            if (__all(ok)) break;
            __builtin_amdgcn_s_sleep(1);
            if (q == 0) vd = agldull(dbase + b);
          }
          if (q == 0)
            out[(size_t)(b0 + b) * S + tlast] =
                ftanh_(s + __uint_as_float((unsigned)vd) + bl0);
        }
      }
    }
  } else {
    if (tid < 16 * (H / 8)) {
      int n = tid / (H / 8), kq = tid % (H / 8);
      uint4 vv = *(const uint4*)(fb + n * HP + kq * 8);
      *(uint4*)(xout + ((size_t)(b0 + n) * S + t0 + Sc - 1) * H + kq * 8) = vv;
    }
  }

  // carry state: own channel range only
  for (int i = tid; i < 16 * HLOC; i += 512) {
    int n = i / HLOC, chl = i % HLOC;
    sth[(size_t)(b0 + n) * H + half * HLOC + chl] = __half2float(fb[n * HP + chl]);
  }
#pragma unroll
  for (int im = 0; im < MTW; ++im) {
    int ch = (mbase + w * MTW + im) * 4 + quad;
    stc[(size_t)(b0 + n16) * H + ch] = cst[im];
  }
}

// Fat pipelined kernel: slot s runs L0(chunk s), L1(chunk s-1), L2(chunk s-2)
// concurrently as disjoint WG ranges; inter-layer deps via dispatch order.
__global__ __launch_bounds__(512) void scan_fat(
    const __half* x0, __half* x1, __half* x2,
    const uint4* wpI0, const uint4* wpI1, const uint4* wpI2,
    const float* bs0, const float* bs1, const float* bs2,
    const uint4* wpH0, const uint4* wpH1, const uint4* wpH2,
    f32x4* preT0, f32x4* preT1, f32x4* preT2,
    float* out, const unsigned* wlp, const float* blp,
    float* sh0, float* sc0, float* sh1, float* sc1, float* sh2, float* sc2,
    unsigned long long* xh, int Sc, int slot, int NC) {
  int b = blockIdx.x;
  if (b < 16) {
    int c = slot;
    if (c >= NC) return;
    scan_body<64, 1, false, 1>(b, x0, wpI0, bs0, wpH0, preT0, x1, nullptr,
                               nullptr, nullptr, sh0, sc0, nullptr, Sc, c * Sc, c == 0);
  } else if (b < 32) {
    int c = slot - 1;
    if (c < 0 || c >= NC) return;
    scan_body<128, 1, false, 2>(b - 16, x1, wpI1, bs1, wpH1, preT1, x2, nullptr,
                                nullptr, nullptr, sh1, sc1, nullptr, Sc, c * Sc, c == 0);
  } else {
    int c = slot - 2;
    if (c < 0 || c >= NC) return;
    scan_body<256, 2, true, 4>(b - 32, x2, wpI2, bs2, wpH2, preT2, nullptr, out,
                               wlp, blp, sh2, sc2, xh, Sc, c * Sc, c == 0);
  }
}

extern "C" void kernel_launch(void* const* d_in, const int* in_sizes, int n_in,
                              void* d_out, int out_size, void* d_ws, size_t ws_size,
                              hipStream_t stream) {
  (void)in_sizes; (void)n_in; (void)out_size;
  const float* noise = (const float*)d_in[0];
  const float* Wih0 = (const float*)d_in[1];
  const float* Whh0 = (const float*)d_in[2];
  const float* bih0 = (const float*)d_in[3];
  const float* bhh0 = (const float*)d_in[4];
  const float* Wih1 = (const float*)d_in[5];
  const float* Whh1 = (const float*)d_in[6];
  const float* bih1 = (const float*)d_in[7];
  const float* bhh1 = (const float*)d_in[8];
  const float* Wih2 = (const float*)d_in[9];
  const float* Whh2 = (const float*)d_in[10];
  const float* bih2 = (const float*)d_in[11];
  const float* bhh2 = (const float*)d_in[12];
  const float* Wl = (const float*)d_in[13];
  const float* bl = (const float*)d_in[14];
  float* out = (float*)d_out;

  char* p = (char*)d_ws;
  auto alloc = [&](size_t bytes) {
    char* r = p;
    p += (bytes + 255) & ~(size_t)255;
    return r;
  };
  // A-frag packed weights (fp16): recurrent + input
  uint4* wpH0 = (uint4*)alloc((size_t)16 * 2 * 1024);
  uint4* wpH1 = (uint4*)alloc((size_t)32 * 4 * 1024);
  uint4* wpH2 = (uint4*)alloc((size_t)64 * 8 * 1024);
  uint4* wpI0 = (uint4*)alloc((size_t)16 * 1 * 1024);
  uint4* wpI1 = (uint4*)alloc((size_t)32 * 2 * 1024);
  uint4* wpI2 = (uint4*)alloc((size_t)64 * 4 * 1024);
  float* bs0 = (float*)alloc(256 * 4);
  float* bs1 = (float*)alloc(512 * 4);
  float* bs2 = (float*)alloc(1024 * 4);
  unsigned* wlp = (unsigned*)alloc(128 * 4);
  // state carry
  float* sh0 = (float*)alloc((size_t)B * H0 * 4);
  float* sc0 = (float*)alloc((size_t)B * H0 * 4);
  float* sh1 = (float*)alloc((size_t)B * H1 * 4);
  float* sc1 = (float*)alloc((size_t)B * H1 * 4);
  float* sh2 = (float*)alloc((size_t)B * H2 * 4);
  float* sc2 = (float*)alloc((size_t)B * H2 * 4);
  // activations (fp16)
  __half* x0 = (__half*)alloc((size_t)B * S * 32 * 2);
  __half* x1 = (__half*)alloc((size_t)B * S * H0 * 2);
  __half* x2 = (__half*)alloc((size_t)B * S * H1 * 2);
  // cross-WG exchange: partial slots (2 par x 16 bt x 2 half x 8192 ull)
  // + dot slots (2 par x 16 bt x 16 ull)
  const size_t XH_ULL = (size_t)2 * 16 * 2 * 8192 + (size_t)2 * 16 * 16;
  unsigned long long* xh = (unsigned long long*)alloc(XH_ULL * 8);
  size_t fixed = (size_t)(p - (char*)d_ws);
  int Sc = 64;  // chunk size; per-layer preT buffers hold ONE chunk each
  while (Sc > 16 && fixed + (size_t)B * Sc * 16 * (H0 + H1 + H2) > ws_size) Sc >>= 1;
  f32x4* preT0 = (f32x4*)alloc((size_t)B * Sc * 16 * H0);
  f32x4* preT1 = (f32x4*)alloc((size_t)B * Sc * 16 * H1);
  f32x4* preT2 = (f32x4*)alloc((size_t)B * Sc * 16 * H2);

  // xh must be zeroed each launch: seq values repeat across graph replays.
  hipMemsetAsync(xh, 0, XH_ULL * 8, stream);

  // ---- packing (every call; deterministic) ----
  pack_frag<<<(16 * 2 * 64 + 255) / 256, 256, 0, stream>>>(Whh0, wpH0, 64, 64, 16, 2);
  pack_frag<<<(32 * 4 * 64 + 255) / 256, 256, 0, stream>>>(Whh1, wpH1, 128, 128, 32, 4);
  pack_frag<<<(64 * 8 * 64 + 255) / 256, 256, 0, stream>>>(Whh2, wpH2, 256, 256, 64, 8);
  pack_frag<<<(16 * 1 * 64 + 255) / 256, 256, 0, stream>>>(Wih0, wpI0, 64, 32, 16, 1);
  pack_frag<<<(32 * 2 * 64 + 255) / 256, 256, 0, stream>>>(Wih1, wpI1, 128, 64, 32, 2);
  pack_frag<<<(64 * 4 * 64 + 255) / 256, 256, 0, stream>>>(Wih2, wpI2, 256, 128, 64, 4);
  pack_bias<<<1, 256, 0, stream>>>(bih0, bhh0, bs0, 64);
  pack_bias<<<2, 256, 0, stream>>>(bih1, bhh1, bs1, 128);
  pack_bias<<<4, 256, 0, stream>>>(bih2, bhh2, bs2, 256);
  pack_wl<<<1, 128, 0, stream>>>(Wl, wlp, 128);
  f2h<<<(B * S * 32 / 8 + 255) / 256, 256, 0, stream>>>(noise, x0, B * S * 32 / 8);

  // ---- pipelined slots: L0(c=s) || L1(c=s-1) || L2(c=s-2) ----
  int NC = S / Sc;
  for (int slot = 0; slot < NC + 2; ++slot)
    scan_fat<<<64, 512, 0, stream>>>(x0, x1, x2, wpI0, wpI1, wpI2, bs0, bs1, bs2,
                                     wpH0, wpH1, wpH2, preT0, preT1, preT2,
                                     out, wlp, bl, sh0, sc0, sh1, sc1, sh2, sc2,
                                     xh, Sc, slot, NC);
}

// Round 7
// 1924.126 us; speedup vs baseline: 1.8892x; 1.8892x over previous
//
#include <hip/hip_runtime.h>
#include <hip/hip_fp16.h>

#define DEVINL __device__ __forceinline__

constexpr int B = 256, S = 512;
constexpr int H0 = 64, H1 = 128, H2 = 256;

typedef _Float16 f16x8 __attribute__((ext_vector_type(8)));
typedef float f32x4 __attribute__((ext_vector_type(4)));
typedef _Float16 h2v __attribute__((ext_vector_type(2)));

DEVINL float fexp2(float x) { return __builtin_amdgcn_exp2f(x); }
DEVINL float frcp(float x) { return __builtin_amdgcn_rcpf(x); }
DEVINL float fsig(float x) { return frcp(1.f + fexp2(-1.44269504088896f * x)); }
DEVINL float ftanh_(float x) { return 1.f - 2.f * frcp(1.f + fexp2(2.88539008177793f * x)); }
DEVINL h2v as_h2(unsigned u) { union { unsigned u; h2v h; } x; x.u = u; return x.h; }
DEVINL float fdot2(unsigned a, unsigned b, float c) {
  return __builtin_amdgcn_fdot2(as_h2(a), as_h2(b), c, false);
}
union FU { uint4 u; f16x8 h; };
DEVINL f16x8 as_f16x8(uint4 u) { FU x; x.u = u; return x.h; }

// Agent-scope (mall-coherent) 8-byte atomic load/store. One aligned dwordx2
// transaction cannot tear, so {seq(hi32) | data(lo32)} travel together and the
// consumer validates seq in-band (R4/R5-proven flagless protocol).
DEVINL unsigned long long agldull(unsigned long long* p) {
  return __hip_atomic_load(p, __ATOMIC_RELAXED, __HIP_MEMORY_SCOPE_AGENT);
}
DEVINL void agstull(unsigned long long* p, unsigned long long v) {
  __hip_atomic_store(p, v, __ATOMIC_RELAXED, __HIP_MEMORY_SCOPE_AGENT);
}

// Row permutation: r' = mt*16 + quad*4 + reg  ->  channel = r'>>2, gate = r'&3.
// orig torch row = gate*Hch + channel. One lane of the C-frag then holds one
// channel's (i,f,g,o) quad (C: col=lane&15, row=(lane>>4)*4+reg).

// Pack W (fp32 [4*Hch][Kdim], torch gate rows) into fp16 A-frag order:
// wp[(mt*KT+kt)*64+lane] = 8 halves of W'[mt*16+(lane&15)][kt*32+(lane>>4)*8+j]
__global__ __launch_bounds__(256) void pack_frag(const float* __restrict__ w,
    uint4* __restrict__ wp, int Hch, int Kdim, int MT, int KT) {
  int o = blockIdx.x * 256 + threadIdx.x;
  if (o >= MT * KT * 64) return;
  int lane = o & 63, fk = o >> 6;
  int kt = fk % KT, mt = fk / KT;
  int rp = mt * 16 + (lane & 15);
  int orig = (rp & 3) * Hch + (rp >> 2);
  int k0 = kt * 32 + (lane >> 4) * 8;
  unsigned r[4];
#pragma unroll
  for (int p = 0; p < 4; ++p) {
    unsigned lo = __half_as_ushort(__float2half_rn(w[(size_t)orig * Kdim + k0 + 2 * p]));
    unsigned hi = __half_as_ushort(__float2half_rn(w[(size_t)orig * Kdim + k0 + 2 * p + 1]));
    r[p] = lo | (hi << 16);
  }
  uint4 v; v.x = r[0]; v.y = r[1]; v.z = r[2]; v.w = r[3];
  wp[o] = v;
}

__global__ __launch_bounds__(256) void pack_bias(const float* __restrict__ bih,
    const float* __restrict__ bhh, float* __restrict__ bs, int Hch) {
  int rp = blockIdx.x * 256 + threadIdx.x;
  if (rp >= 4 * Hch) return;
  int orig = (rp & 3) * Hch + (rp >> 2);
  bs[rp] = bih[orig] + bhh[orig];
}

__global__ void pack_wl(const float* __restrict__ wl, unsigned* __restrict__ wlp, int n) {
  int i = threadIdx.x;
  if (i < n) {
    unsigned lo = __half_as_ushort(__float2half_rn(wl[2 * i]));
    unsigned hi = __half_as_ushort(__float2half_rn(wl[2 * i + 1]));
    wlp[i] = lo | (hi << 16);
  }
}

__global__ __launch_bounds__(256) void f2h(const float* __restrict__ x,
                                           __half* __restrict__ y, int n8) {
  int i = blockIdx.x * 256 + threadIdx.x;
  if (i >= n8) return;
  float4 a = *(const float4*)(x + i * 8);
  float4 b = *(const float4*)(x + i * 8 + 4);
  __half h[8];
  h[0] = __float2half_rn(a.x); h[1] = __float2half_rn(a.y);
  h[2] = __float2half_rn(a.z); h[3] = __float2half_rn(a.w);
  h[4] = __float2half_rn(b.x); h[5] = __float2half_rn(b.y);
  h[6] = __float2half_rn(b.z); h[7] = __float2half_rn(b.w);
  *(uint4*)(y + i * 8) = *(const uint4*)h;
}

// K-block over a compile-time k-tile range reading B-frags from buffer BUF.
#define KBLK(BUF, K0, K1)                                                           \
  _Pragma("unroll") for (int kt = (K0); kt < (K1); ++kt) {                          \
    f16x8 bfrag = as_f16x8(*(const uint4*)((BUF) + n16 * HP + kt * 32 + quad * 8)); \
    _Pragma("unroll") for (int im = 0; im < MTW; ++im)                              \
      acc[im] = __builtin_amdgcn_mfma_f32_16x16x32_f16(                             \
          as_f16x8(areg[im][kt]), bfrag, acc[im], 0, 0, 0);                         \
  }

// One layer-stage. SPLIT=1 (L0/L1): input GEMM FUSED into the scan step
// (acc = bias + Wih*x(t) + Whh*h(t-1)); no preT traffic; hb double-buffered,
// ONE barrier/step. SPLIT=2 (L2): R5-proven structure — embedded GEMM phase ->
// preT, then scan with flagless seq-tagged h-half exchange. Import loads are
// issued at the END of the PREVIOUS step (right after our own export): the
// symmetric peer exports at the same point, so by validate time the data has
// usually landed -> first-check hit, no wasted round-trip. Tight spin retry.
template <int H, int SPLIT, bool FINAL, int KTI>
DEVINL void scan_body(
    int bx, const __half* x, const uint4* wpI, const float* bs,
    const uint4* wp, f32x4* preT, __half* xout, float* out,
    const unsigned* wlp, const float* blp,
    float* sth, float* stc, unsigned long long* xh,
    int Sc, int t0, int first) {
  constexpr int MT = H / 4;          // total m-tiles
  constexpr int MTO = MT / SPLIT;    // owned m-tiles
  constexpr int MTW = MTO / 8;       // per wave
  constexpr int KT = H / 32;
  constexpr int HP = H + 8;
  constexpr int CH_OWN = MTO * 4;    // owned channels
  constexpr int KI = KTI * 32;

  __shared__ __half hb[2][16 * HP];
  __shared__ unsigned wls[FINAL ? H / 2 : 1];

  const int tid = threadIdx.x, w = tid >> 6, lane = tid & 63;
  const int n16 = lane & 15, quad = lane >> 4;
  int bt, half;
  if constexpr (SPLIT == 2) { bt = bx & 15; half = bx >> 4; }
  else { bt = bx; half = 0; }
  const int b0 = bt * 16;
  const int mbase = half * MTO;

  // ---- SPLIT=2: embedded input GEMM phase -> preT (R5-proven) ----
  if constexpr (SPLIT == 2) {
    uint4 wih[MTW][KTI];
#pragma unroll
    for (int im = 0; im < MTW; ++im)
#pragma unroll
      for (int kt = 0; kt < KTI; ++kt)
        wih[im][kt] = wpI[((size_t)(mbase + w * MTW + im) * KTI + kt) * 64 + lane];
    f32x4 bini[MTW];
#pragma unroll
    for (int im = 0; im < MTW; ++im)
      bini[im] = *(const f32x4*)(bs + (mbase + w * MTW + im) * 16 + quad * 4);
    uint4 bfr[KTI];
    {
      const __half* xr = x + ((size_t)(b0 + n16) * S + t0) * KI + quad * 8;
#pragma unroll
      for (int kt = 0; kt < KTI; ++kt) bfr[kt] = *(const uint4*)(xr + kt * 32);
    }
    for (int t = 0; t < Sc; ++t) {
      uint4 cur[KTI];
#pragma unroll
      for (int kt = 0; kt < KTI; ++kt) cur[kt] = bfr[kt];
      if (t + 1 < Sc) {
        const __half* xr = x + ((size_t)(b0 + n16) * S + t0 + t + 1) * KI + quad * 8;
#pragma unroll
        for (int kt = 0; kt < KTI; ++kt) bfr[kt] = *(const uint4*)(xr + kt * 32);
      }
      f32x4 ac[MTW];
#pragma unroll
      for (int im = 0; im < MTW; ++im) ac[im] = bini[im];
#pragma unroll
      for (int kt = 0; kt < KTI; ++kt)
#pragma unroll
        for (int im = 0; im < MTW; ++im)
          ac[im] = __builtin_amdgcn_mfma_f32_16x16x32_f16(as_f16x8(wih[im][kt]),
                                                          as_f16x8(cur[kt]), ac[im], 0, 0, 0);
#pragma unroll
      for (int im = 0; im < MTW; ++im)
        preT[((size_t)(bt * Sc + t) * MT + mbase + w * MTW + im) * 64 + lane] = ac[im];
    }
    asm volatile("s_waitcnt vmcnt(0)" ::: "memory");  // preT at L2 before re-read
  }

  // ---- SPLIT=1: persistent input-GEMM weights (fused path) ----
  uint4 wih1[SPLIT == 1 ? MTW : 1][SPLIT == 1 ? KTI : 1];
  f32x4 bini1[SPLIT == 1 ? MTW : 1];
  if constexpr (SPLIT == 1) {
#pragma unroll
    for (int im = 0; im < MTW; ++im)
#pragma unroll
      for (int kt = 0; kt < KTI; ++kt)
        wih1[im][kt] = wpI[((size_t)(w * MTW + im) * KTI + kt) * 64 + lane];
#pragma unroll
    for (int im = 0; im < MTW; ++im)
      bini1[im] = *(const f32x4*)(bs + (w * MTW + im) * 16 + quad * 4);
  }

  // ---- scan phase ----
  uint4 areg[MTW][KT];
#pragma unroll
  for (int im = 0; im < MTW; ++im)
#pragma unroll
    for (int kt = 0; kt < KT; ++kt)
      areg[im][kt] = wp[((size_t)(mbase + w * MTW + im) * KT + kt) * 64 + lane];

  if constexpr (FINAL)
    for (int i = tid; i < H / 2; i += 512) wls[i] = wlp[i];

  float cst[MTW];
#pragma unroll
  for (int im = 0; im < MTW; ++im) {
    int ch = (mbase + w * MTW + im) * 4 + quad;
    cst[im] = first ? 0.f : stc[(size_t)(b0 + n16) * H + ch];
  }
  for (int i = tid; i < 16 * H; i += 512) {
    int n = i / H, ch = i % H;
    hb[0][n * HP + ch] = first ? __float2half_rn(0.f)
                               : __float2half_rn(sth[(size_t)(b0 + n) * H + ch]);
  }
  __syncthreads();

  const float bl0 = FINAL ? blp[0] : 0.f;

  auto emit_out = [&](const __half* rbuf, int t_out) {
    if constexpr (FINAL) {
      if ((SPLIT == 1 || half == 0) && tid < 128) {
        int n = tid >> 3, seg = tid & 7;
        const unsigned* hrow = (const unsigned*)(rbuf + n * HP);
        float s = 0.f;
#pragma unroll
        for (int p = 0; p < 16; ++p) s = fdot2(hrow[seg * 16 + p], wls[seg * 16 + p], s);
        s += __shfl_xor(s, 1); s += __shfl_xor(s, 2); s += __shfl_xor(s, 4);
        if (seg == 0) out[(size_t)(b0 + n) * S + t_out] = ftanh_(s + bl0);
      }
    } else {
      if (tid < 16 * (H / 8)) {
        int n = tid / (H / 8), kq = tid % (H / 8);
        uint4 v = *(const uint4*)(rbuf + n * HP + kq * 8);
        *(uint4*)(xout + ((size_t)(b0 + n) * S + t_out) * H + kq * 8) = v;
      }
    }
  };

  // SPLIT=2: preT prefetch; SPLIT=1: x prefetch
  f32x4 nxt[MTW];
  if constexpr (SPLIT == 2) {
#pragma unroll
    for (int im = 0; im < MTW; ++im)
      nxt[im] = preT[((size_t)(bt * Sc) * MT + mbase + w * MTW + im) * 64 + lane];
  }
  uint4 xcur[SPLIT == 1 ? KTI : 1];
  if constexpr (SPLIT == 1) {
    const __half* xr = x + ((size_t)(b0 + n16) * S + t0) * KI + quad * 8;
#pragma unroll
    for (int kt = 0; kt < KTI; ++kt) xcur[kt] = *(const uint4*)(xr + kt * 32);
  }

  // SPLIT=2 deferred-import registers (issued end of previous step)
  unsigned long long v0 = 0, v1 = 0;
  const int j0 = w * 128 + lane;

  for (int tl = 0; tl < Sc; ++tl) {
    __half* rb = hb[tl & 1];        // h(tl-1)
    __half* wb = hb[(tl + 1) & 1];  // receives h(tl)
    const int hid = t0 + tl;
    f32x4 acc[MTW];

    if constexpr (SPLIT == 2) {
#pragma unroll
      for (int im = 0; im < MTW; ++im) acc[im] = nxt[im];
      if (tl + 1 < Sc) {
#pragma unroll
        for (int im = 0; im < MTW; ++im)
          nxt[im] = preT[((size_t)(bt * Sc + tl + 1) * MT + mbase + w * MTW + im) * 64 + lane];
      }

      // own-half k-tiles first; deferred import (v0,v1) validated after.
      if (half == 0) { KBLK(rb, 0, KT / 2) } else { KBLK(rb, KT / 2, KT) }
      if (tl > 0) {
        const unsigned seq = (unsigned)hid;  // = (hid-1)+1
        unsigned long long* srcp =
            xh + (((size_t)((hid - 1) & 1) * 16 + bt) * 2 + (1 - half)) * 1024;
        for (;;) {
          bool ok = ((unsigned)(v0 >> 32) == seq) & ((unsigned)(v1 >> 32) == seq);
          if (__all(ok)) break;
          v0 = agldull(srcp + j0);
          v1 = agldull(srcp + j0 + 64);
        }
        int c0 = j0 >> 3, dn0 = j0 & 7;  // dword j = c*8 + dn; batches 2dn,2dn+1
        rb[(2 * dn0) * HP + (1 - half) * CH_OWN + c0] =
            __ushort_as_half((unsigned short)(v0 & 0xffffu));
        rb[(2 * dn0 + 1) * HP + (1 - half) * CH_OWN + c0] =
            __ushort_as_half((unsigned short)((v0 >> 16) & 0xffffu));
        int j1 = j0 + 64, c1 = j1 >> 3, dn1 = j1 & 7;
        rb[(2 * dn1) * HP + (1 - half) * CH_OWN + c1] =
            __ushort_as_half((unsigned short)(v1 & 0xffffu));
        rb[(2 * dn1 + 1) * HP + (1 - half) * CH_OWN + c1] =
            __ushort_as_half((unsigned short)((v1 >> 16) & 0xffffu));
        __syncthreads();  // [#1] peer half of h(tl-1) visible
      }
      if (half == 0) { KBLK(rb, KT / 2, KT) } else { KBLK(rb, 0, KT / 2) }
      if (tl > 0) emit_out(rb, hid - 1);  // full h(tl-1) in rb
    } else {
      // SPLIT=1 fused: issue next x loads, GEMM from xcur, then recurrent.
      uint4 xnxt[KTI];
      if (tl + 1 < Sc) {
        const __half* xr = x + ((size_t)(b0 + n16) * S + hid + 1) * KI + quad * 8;
#pragma unroll
        for (int kt = 0; kt < KTI; ++kt) xnxt[kt] = *(const uint4*)(xr + kt * 32);
      }
#pragma unroll
      for (int im = 0; im < MTW; ++im) acc[im] = bini1[im];
#pragma unroll
      for (int kt = 0; kt < KTI; ++kt)
#pragma unroll
        for (int im = 0; im < MTW; ++im)
          acc[im] = __builtin_amdgcn_mfma_f32_16x16x32_f16(as_f16x8(wih1[im][kt]),
                                                           as_f16x8(xcur[kt]), acc[im], 0, 0, 0);
      if (tl > 0) emit_out(rb, hid - 1);
      KBLK(rb, 0, KT)
      if (tl + 1 < Sc) {
#pragma unroll
        for (int kt = 0; kt < KTI; ++kt) xcur[kt] = xnxt[kt];
      }
    }

    // gates (lane holds one channel's i,f,g,o per m-tile)
    __half hh[MTW];
#pragma unroll
    for (int im = 0; im < MTW; ++im) {
      float gi = fsig(acc[im][0]);
      float gf = fsig(acc[im][1]);
      float gg = ftanh_(acc[im][2]);
      float go = fsig(acc[im][3]);
      float cn = gf * cst[im] + gi * gg;
      cst[im] = cn;
      hh[im] = __float2half_rn(go * ftanh_(cn));
    }

    if constexpr (SPLIT == 2) {
      // export h(tl): lanes (2k,2k+1) pack one dword via shfl_xor(1), tagged.
      const unsigned eseq = (unsigned)(hid + 1);
      unsigned long long* dst =
          xh + (((size_t)(hid & 1) * 16 + bt) * 2 + half) * 1024;
#pragma unroll
      for (int im = 0; im < MTW; ++im) {
        unsigned m = (unsigned)__half_as_ushort(hh[im]);
        unsigned o = (unsigned)__shfl_xor((int)m, 1);
        if (!(lane & 1)) {
          int cl = (w * MTW + im) * 4 + quad;  // channel local to this half
          agstull(dst + cl * 8 + (n16 >> 1),
                  ((unsigned long long)eseq << 32) | (unsigned long long)(m | (o << 16)));
        }
      }
      // deferred import ISSUE for next step (peer h(tl)); validated next iter.
      {
        unsigned long long* srcn =
            xh + (((size_t)(hid & 1) * 16 + bt) * 2 + (1 - half)) * 1024;
        v0 = agldull(srcn + j0);
        v1 = agldull(srcn + j0 + 64);
      }
#pragma unroll
      for (int im = 0; im < MTW; ++im)
        wb[n16 * HP + (mbase + w * MTW + im) * 4 + quad] = hh[im];
      __syncthreads();  // [#2] own half of h(tl) ready; rb reads done
    } else {
#pragma unroll
      for (int im = 0; im < MTW; ++im)
        wb[n16 * HP + (w * MTW + im) * 4 + quad] = hh[im];
      __syncthreads();  // single barrier/step (double-buffered hb)
    }
  }

  __half* fb = hb[Sc & 1];  // holds own half of h(Sc-1)
  if constexpr (SPLIT == 2) {
    // tail: validate deferred import of peer half of h(Sc-1)
    const unsigned seq = (unsigned)(t0 + Sc);
    unsigned long long* srcp =
        xh + (((size_t)((t0 + Sc - 1) & 1) * 16 + bt) * 2 + (1 - half)) * 1024;
    for (;;) {
      bool ok = ((unsigned)(v0 >> 32) == seq) & ((unsigned)(v1 >> 32) == seq);
      if (__all(ok)) break;
      v0 = agldull(srcp + j0);
      v1 = agldull(srcp + j0 + 64);
    }
    int c0 = j0 >> 3, dn0 = j0 & 7;
    fb[(2 * dn0) * HP + (1 - half) * CH_OWN + c0] =
        __ushort_as_half((unsigned short)(v0 & 0xffffu));
    fb[(2 * dn0 + 1) * HP + (1 - half) * CH_OWN + c0] =
        __ushort_as_half((unsigned short)((v0 >> 16) & 0xffffu));
    int j1 = j0 + 64, c1 = j1 >> 3, dn1 = j1 & 7;
    fb[(2 * dn1) * HP + (1 - half) * CH_OWN + c1] =
        __ushort_as_half((unsigned short)(v1 & 0xffffu));
    fb[(2 * dn1 + 1) * HP + (1 - half) * CH_OWN + c1] =
        __ushort_as_half((unsigned short)((v1 >> 16) & 0xffffu));
    __syncthreads();
  }

  emit_out(fb, t0 + Sc - 1);

  // carry state (sth full range — duplicate identical writes for SPLIT=2 benign)
  for (int i = tid; i < 16 * H; i += 512) {
    int n = i / H, ch = i % H;
    sth[(size_t)(b0 + n) * H + ch] = __half2float(fb[n * HP + ch]);
  }
#pragma unroll
  for (int im = 0; im < MTW; ++im) {
    int ch = (mbase + w * MTW + im) * 4 + quad;
    stc[(size_t)(b0 + n16) * H + ch] = cst[im];
  }
}
#undef KBLK

// Fat pipelined kernel: slot s runs L0(chunk s), L1(chunk s-1), L2(chunk s-2)
// concurrently as disjoint WG ranges; inter-layer deps via dispatch order.
__global__ __launch_bounds__(512) void scan_fat(
    const __half* x0, __half* x1, __half* x2,
    const uint4* wpI0, const uint4* wpI1, const uint4* wpI2,
    const float* bs0, const float* bs1, const float* bs2,
    const uint4* wpH0, const uint4* wpH1, const uint4* wpH2,
    f32x4* preT2,
    float* out, const unsigned* wlp, const float* blp,
    float* sh0, float* sc0, float* sh1, float* sc1, float* sh2, float* sc2,
    unsigned long long* xh, int Sc, int slot, int NC) {
  int b = blockIdx.x;
  if (b < 16) {
    int c = slot;
    if (c >= NC) return;
    scan_body<64, 1, false, 1>(b, x0, wpI0, bs0, wpH0, nullptr, x1, nullptr,
                               nullptr, nullptr, sh0, sc0, nullptr, Sc, c * Sc, c == 0);
  } else if (b < 32) {
    int c = slot - 1;
    if (c < 0 || c >= NC) return;
    scan_body<128, 1, false, 2>(b - 16, x1, wpI1, bs1, wpH1, nullptr, x2, nullptr,
                                nullptr, nullptr, sh1, sc1, nullptr, Sc, c * Sc, c == 0);
  } else {
    int c = slot - 2;
    if (c < 0 || c >= NC) return;
    scan_body<256, 2, true, 4>(b - 32, x2, wpI2, bs2, wpH2, preT2, nullptr, out,
                               wlp, blp, sh2, sc2, xh, Sc, c * Sc, c == 0);
  }
}

extern "C" void kernel_launch(void* const* d_in, const int* in_sizes, int n_in,
                              void* d_out, int out_size, void* d_ws, size_t ws_size,
                              hipStream_t stream) {
  (void)in_sizes; (void)n_in; (void)out_size;
  const float* noise = (const float*)d_in[0];
  const float* Wih0 = (const float*)d_in[1];
  const float* Whh0 = (const float*)d_in[2];
  const float* bih0 = (const float*)d_in[3];
  const float* bhh0 = (const float*)d_in[4];
  const float* Wih1 = (const float*)d_in[5];
  const float* Whh1 = (const float*)d_in[6];
  const float* bih1 = (const float*)d_in[7];
  const float* bhh1 = (const float*)d_in[8];
  const float* Wih2 = (const float*)d_in[9];
  const float* Whh2 = (const float*)d_in[10];
  const float* bih2 = (const float*)d_in[11];
  const float* bhh2 = (const float*)d_in[12];
  const float* Wl = (const float*)d_in[13];
  const float* bl = (const float*)d_in[14];
  float* out = (float*)d_out;

  char* p = (char*)d_ws;
  auto alloc = [&](size_t bytes) {
    char* r = p;
    p += (bytes + 255) & ~(size_t)255;
    return r;
  };
  // A-frag packed weights (fp16): recurrent + input
  uint4* wpH0 = (uint4*)alloc((size_t)16 * 2 * 1024);
  uint4* wpH1 = (uint4*)alloc((size_t)32 * 4 * 1024);
  uint4* wpH2 = (uint4*)alloc((size_t)64 * 8 * 1024);
  uint4* wpI0 = (uint4*)alloc((size_t)16 * 1 * 1024);
  uint4* wpI1 = (uint4*)alloc((size_t)32 * 2 * 1024);
  uint4* wpI2 = (uint4*)alloc((size_t)64 * 4 * 1024);
  float* bs0 = (float*)alloc(256 * 4);
  float* bs1 = (float*)alloc(512 * 4);
  float* bs2 = (float*)alloc(1024 * 4);
  unsigned* wlp = (unsigned*)alloc(128 * 4);
  // state carry
  float* sh0 = (float*)alloc((size_t)B * H0 * 4);
  float* sc0 = (float*)alloc((size_t)B * H0 * 4);
  float* sh1 = (float*)alloc((size_t)B * H1 * 4);
  float* sc1 = (float*)alloc((size_t)B * H1 * 4);
  float* sh2 = (float*)alloc((size_t)B * H2 * 4);
  float* sc2 = (float*)alloc((size_t)B * H2 * 4);
  // activations (fp16)
  __half* x0 = (__half*)alloc((size_t)B * S * 32 * 2);
  __half* x1 = (__half*)alloc((size_t)B * S * H0 * 2);
  __half* x2 = (__half*)alloc((size_t)B * S * H1 * 2);
  // cross-WG exchange: {seq|data} ull per dword-pair, 2 parity x 16 bt x 2 half
  unsigned long long* xh = (unsigned long long*)alloc((size_t)2 * 16 * 2 * 1024 * 8);
  size_t fixed = (size_t)(p - (char*)d_ws);
  int Sc = 64;  // chunk size; preT2 holds ONE chunk (L2 only — L0/L1 fused)
  while (Sc > 16 && fixed + (size_t)B * Sc * 16 * H2 > ws_size) Sc >>= 1;
  f32x4* preT2 = (f32x4*)alloc((size_t)B * Sc * 16 * H2);

  // xh must be zeroed each launch: seq values repeat across graph replays.
  hipMemsetAsync(xh, 0, (size_t)2 * 16 * 2 * 1024 * 8, stream);

  // ---- packing (every call; deterministic) ----
  pack_frag<<<(16 * 2 * 64 + 255) / 256, 256, 0, stream>>>(Whh0, wpH0, 64, 64, 16, 2);
  pack_frag<<<(32 * 4 * 64 + 255) / 256, 256, 0, stream>>>(Whh1, wpH1, 128, 128, 32, 4);
  pack_frag<<<(64 * 8 * 64 + 255) / 256, 256, 0, stream>>>(Whh2, wpH2, 256, 256, 64, 8);
  pack_frag<<<(16 * 1 * 64 + 255) / 256, 256, 0, stream>>>(Wih0, wpI0, 64, 32, 16, 1);
  pack_frag<<<(32 * 2 * 64 + 255) / 256, 256, 0, stream>>>(Wih1, wpI1, 128, 64, 32, 2);
  pack_frag<<<(64 * 4 * 64 + 255) / 256, 256, 0, stream>>>(Wih2, wpI2, 256, 128, 64, 4);
  pack_bias<<<1, 256, 0, stream>>>(bih0, bhh0, bs0, 64);
  pack_bias<<<2, 256, 0, stream>>>(bih1, bhh1, bs1, 128);
  pack_bias<<<4, 256, 0, stream>>>(bih2, bhh2, bs2, 256);
  pack_wl<<<1, 128, 0, stream>>>(Wl, wlp, 128);
  f2h<<<(B * S * 32 / 8 + 255) / 256, 256, 0, stream>>>(noise, x0, B * S * 32 / 8);

  // ---- pipelined slots: L0(c=s) || L1(c=s-1) || L2(c=s-2) ----
  int NC = S / Sc;
  for (int slot = 0; slot < NC + 2; ++slot)
    scan_fat<<<64, 512, 0, stream>>>(x0, x1, x2, wpI0, wpI1, wpI2, bs0, bs1, bs2,
                                     wpH0, wpH1, wpH2, preT2,
                                     out, wlp, bl, sh0, sc0, sh1, sc1, sh2, sc2,
                                     xh, Sc, slot, NC);
}